// Round 13
// baseline (76.213 us; speedup 1.0000x reference)
//
#include <hip/hip_runtime.h>
#include <hip/hip_bf16.h>

#define HW 3136            // 56*56
#define NPIX 50176         // 16*3136

typedef __attribute__((ext_vector_type(8))) _Float16 f16x8;
typedef __attribute__((ext_vector_type(4))) float f32x4;
typedef __attribute__((ext_vector_type(8))) unsigned short u16x8;

__device__ inline unsigned short f2h(float v){
    _Float16 h = (_Float16)v;
    union { _Float16 h; unsigned short u; } cv; cv.h = h; return cv.u;
}
__device__ inline float h2f(unsigned short u){
    union { unsigned short u; _Float16 h; } cv; cv.u = u; return (float)cv.h;
}

// ================= prep: xpad + w1t only =================
// A (blocks 0..271):   x -> xpad[plane][68][72] fp16, zero halo
// B (blocks 272..320): w1 -> w1t[g][tap][oc][32ic] fp16
__global__ __launch_bounds__(256) void prep_all(
    const float* __restrict__ x, const float* __restrict__ w1,
    unsigned short* __restrict__ w1t, unsigned short* __restrict__ xpad)
{
    int bb = blockIdx.x;
    if (bb < 272) {
        int t2 = bb * 256 + threadIdx.x;          // < 69632
        int plane = t2 / 68; int r = t2 - plane * 68;
        unsigned short* dst = xpad + ((size_t)plane * 68 + r) * 72;
        int h = r - 6;
        alignas(16) unsigned short tmp[72];
#pragma unroll
        for (int i = 0; i < 72; ++i) tmp[i] = 0;
        if (h >= 0 && h < 56) {
            const float* src = x + (size_t)plane * HW + h * 56;
#pragma unroll
            for (int wq = 0; wq < 56; ++wq) tmp[6 + wq] = f2h(src[wq]);
        }
#pragma unroll
        for (int k = 0; k < 9; ++k)
            *(u16x8*)(dst + k * 8) = *(const u16x8*)(tmp + k * 8);
    } else {
        int t = (bb - 272) * 256 + threadIdx.x;   // < 12544 = 2*49*128
        if (t < 2 * 49 * 128) {
            int g = t / (49 * 128);
            int r = t - g * 49 * 128;
            int tap = r / 128; int oc = r - tap * 128;
            unsigned short* dst = w1t + (size_t)t * 32;
            for (int ic = 0; ic < 32; ++ic)
                dst[ic] = f2h(w1[((size_t)oc * 64 + g * 32 + ic) * 49 + tap]);
        }
    }
}

// ================= conv1(full K, dual-resident halves) + conv2 + softmax =================
// grid 224 = (b16, rg14); block 512 = 8 waves; waves 0-3: g=0, waves 4-7: g=1
// each wave: 112px x 64oc (7mt x 4nt), 49 taps, no mid-loop barriers
// r9-proven schedule: A dbuf, B tri-buf (distance 2), sched_barrier pins + setprio
// Staging reads xpad (fp16, w-contiguous, halo pre-zeroed) with in-LDS transpose
// LDS: 2 planes x 16rows x 68sites x 72B = 156672 B (1 block/CU)
#define LOADA(Abuf, tap) do {                                                 \
    const int p_ = (tap) / 7, q_ = (tap) - 7 * ((tap) / 7);                   \
    const int off_ = p_ * 9792 + q_ * 144;                                    \
    _Pragma("unroll")                                                         \
    for (int mt = 0; mt < 7; ++mt)                                            \
        Abuf[mt] = *(const f16x8*)(smem + abase[mt] + off_);                  \
    } while (0)

#define LOADB(Bbuf, tap) do {                                                 \
    const unsigned short* p_ = wb + (size_t)(tap) * 4096;                     \
    Bbuf[0] = *(const f16x8*)(p_);                                            \
    Bbuf[1] = *(const f16x8*)(p_ + 512);                                      \
    Bbuf[2] = *(const f16x8*)(p_ + 1024);                                     \
    Bbuf[3] = *(const f16x8*)(p_ + 1536);                                     \
    } while (0)

#define DOMFMA(Abuf, Bbuf) do {                                               \
    __builtin_amdgcn_s_setprio(1);                                            \
    _Pragma("unroll")                                                         \
    for (int mt = 0; mt < 7; ++mt) {                                          \
        acc[mt][0] = __builtin_amdgcn_mfma_f32_16x16x32_f16(Abuf[mt], Bbuf[0], acc[mt][0], 0, 0, 0); \
        acc[mt][1] = __builtin_amdgcn_mfma_f32_16x16x32_f16(Abuf[mt], Bbuf[1], acc[mt][1], 0, 0, 0); \
        acc[mt][2] = __builtin_amdgcn_mfma_f32_16x16x32_f16(Abuf[mt], Bbuf[2], acc[mt][2], 0, 0, 0); \
        acc[mt][3] = __builtin_amdgcn_mfma_f32_16x16x32_f16(Abuf[mt], Bbuf[3], acc[mt][3], 0, 0, 0); \
    }                                                                         \
    __builtin_amdgcn_s_setprio(0);                                            \
    } while (0)

__global__ __launch_bounds__(512, 2) void conv_full(
    const unsigned short* __restrict__ xpad, const unsigned short* __restrict__ w1t,
    const float* __restrict__ b1, const float* __restrict__ w2,
    const float* __restrict__ b2, unsigned short* __restrict__ attn)
{
    __shared__ char smem[156672];                      // 2 x 78336
    unsigned short* k1sa = (unsigned short*)smem;            // [224][136] 60928 B (epilogue)
    unsigned short* w2s  = (unsigned short*)(smem + 60928);  // [64][136]  17408 B
    unsigned short* k1sb = (unsigned short*)(smem + 78336);  // [224][136] 60928 B

    const int blk = blockIdx.x;
    const int b   = blk / 14; const int rg = blk - b * 14;
    const int h0  = rg * 4;
    const int tid = threadIdx.x;
    const int lane = tid & 63, warp = tid >> 6;        // 8 waves
    const int g   = warp >> 2;                         // ic-half
    const int wm  = (warp >> 1) & 1, wn = warp & 1;
    const int oc0 = wn * 64;
    const int li  = lane & 15, j = lane >> 4;

    // ---- stage from xpad: in-LDS transpose (w-major -> site-major) ----
    // unit i in [0,9216): c = i/144; rem = i%144; row = rem/9; u9 = rem%9
    // src row (h0+row) of plane (b*64+c) — halo rows/cols pre-zeroed in xpad.
    // every byte of both LDS planes is written => no zero-init, no extra barrier
    const unsigned short* xpb = xpad + (size_t)b * 64 * (68 * 72);
#pragma unroll
    for (int u = 0; u < 18; ++u) {
        int i = u * 512 + tid;
        int c = i / 144; int rem = i - c * 144;
        int row = rem / 9; int u9 = rem - row * 9;
        u16x8 v = *(const u16x8*)(xpb + ((size_t)c * 68 + (h0 + row)) * 72 + u9 * 8);
        int pl = c >> 5, chunk = (c >> 3) & 3, icl = c & 7;
        char* base = smem + pl * 78336 + row * 4896 + chunk * 16 + icl * 2;
#pragma unroll
        for (int e = 0; e < 8; ++e) {
            int m = u9 * 8 + e;
            if (m < 68)
                *(unsigned short*)(base + m * 72) = v[e];
        }
    }
    __syncthreads();

    // ---- A base addresses (fixed across all taps; include plane offset) ----
    int abase[7];
#pragma unroll
    for (int mt = 0; mt < 7; ++mt) {
        int local = wm * 112 + mt * 16 + li;           // 0..223
        int rb = local / 56; int wp = local - rb * 56;
        abase[mt] = g * 78336 + (rb * 68 + wp) * 72 + j * 16;
    }

    f32x4 acc[7][4];
#pragma unroll
    for (int mt = 0; mt < 7; ++mt)
#pragma unroll
        for (int nt = 0; nt < 4; ++nt)
#pragma unroll
            for (int c = 0; c < 4; ++c) acc[mt][nt][c] = 0.f;

    // B base: w1t[g][tap][oc][32], oc = oc0 + li (+nt*16 via imm)
    const unsigned short* wb = w1t + ((size_t)g * 49 * 128 + oc0 + li) * 32 + j * 8;

    // ---- 49-tap fully-unrolled loop; A dbuf, B tri-buf (distance 2), pinned ----
    {
        f16x8 A[2][7], B[3][4];
        LOADA(A[0], 0); LOADB(B[0], 0); LOADB(B[1], 1);
#pragma unroll
        for (int t = 0; t < 49; ++t) {
            if (t < 48) LOADA(A[(t + 1) & 1], t + 1);
            if (t < 47) LOADB(B[(t + 2) % 3], t + 2);
            __builtin_amdgcn_sched_barrier(0);
            DOMFMA(A[t & 1], B[t % 3]);
            __builtin_amdgcn_sched_barrier(0);
        }
    }

    // ---- issue w2 loads (after tap loop; covered by epilogue k1 writes) ----
    f32x4 wv[4];
#pragma unroll
    for (int u = 0; u < 4; ++u) {
        int idx = u * 512 + tid;                       // f32x4 index, < 1568
        wv[u] = (idx < 1568) ? *(const f32x4*)(w2 + (size_t)idx * 4)
                             : (f32x4){0.f, 0.f, 0.f, 0.f};
    }

    __syncthreads();          // all staging readers done; LDS can be overlaid

    // ---- epilogue phase A: write k1 partials + w2s ----
    // g0 waves -> k1sa (+bias); g1 waves -> k1sb (no bias)
    {
        unsigned short* kb = g ? k1sb : k1sa;
        const int pixbase = wm * 112;
#pragma unroll
        for (int nt = 0; nt < 4; ++nt) {
            int oc = oc0 + nt * 16 + li;
            float bias = g ? 0.f : b1[oc];
#pragma unroll
            for (int mt = 0; mt < 7; ++mt) {
#pragma unroll
                for (int i = 0; i < 4; ++i) {
                    int px = pixbase + mt * 16 + j * 4 + i;
                    kb[px * 136 + oc] = f2h(acc[mt][nt][i] + bias);
                }
            }
        }
    }
    // w2s [64 taps][136] fp16 (rows >=49 garbage, masked later)
#pragma unroll
    for (int u = 0; u < 4; ++u) {
        int idx = u * 512 + tid;
        if (idx < 1568) {
            int a = idx / 32; int c0 = (idx - a * 32) * 4;
            alignas(8) unsigned short t4[4];
#pragma unroll
            for (int e = 0; e < 4; ++e) t4[e] = f2h(wv[u][e]);
            *(unsigned long long*)(w2s + a * 136 + c0) = *(const unsigned long long*)t4;
        }
    }
    __syncthreads();

    // ---- conv2: L[tap][px] = w2 @ (k1a + k1b), softmax over taps, -> attn fp16 ----
    // 14 px-tiles over 8 waves: waves 0..5 take 2, waves 6,7 take 1
    const int start = (warp < 6) ? warp * 2 : 12 + (warp - 6);
    const int cnt   = (warp < 6) ? 2 : 1;
    unsigned short* ab = attn + (size_t)b * 49 * HW;

#pragma unroll
    for (int u = 0; u < 2; ++u) {
        if (u < cnt) {
            int pxt = start + u;
            f32x4 a2[4];
#pragma unroll
            for (int tt = 0; tt < 4; ++tt)
#pragma unroll
                for (int c = 0; c < 4; ++c) a2[tt][c] = 0.f;
#pragma unroll
            for (int ks = 0; ks < 4; ++ks) {
                const f16x8 ba = *(const f16x8*)(k1sa + (pxt * 16 + li) * 136 + ks * 32 + j * 8);
                const f16x8 bbv = *(const f16x8*)(k1sb + (pxt * 16 + li) * 136 + ks * 32 + j * 8);
                const f16x8 bf = ba + bbv;             // packed fp16 add
#pragma unroll
                for (int tt = 0; tt < 4; ++tt) {
                    const f16x8 af = *(const f16x8*)(w2s + (tt * 16 + li) * 136 + ks * 32 + j * 8);
                    a2[tt] = __builtin_amdgcn_mfma_f32_16x16x32_f16(af, bf, a2[tt], 0, 0, 0);
                }
            }
            // softmax over taps (rows) for pixel col li
            float mx = -3e38f;
#pragma unroll
            for (int tt = 0; tt < 4; ++tt)
#pragma unroll
                for (int i = 0; i < 4; ++i) {
                    int r = tt * 16 + j * 4 + i;
                    float v = a2[tt][i] + ((r < 49) ? b2[r] : 0.f);
                    a2[tt][i] = v;
                    if (r < 49) mx = fmaxf(mx, v);
                }
            mx = fmaxf(mx, __shfl_xor(mx, 16));
            mx = fmaxf(mx, __shfl_xor(mx, 32));
            float sum = 0.f; float ex[16];
#pragma unroll
            for (int tt = 0; tt < 4; ++tt)
#pragma unroll
                for (int i = 0; i < 4; ++i) {
                    int r = tt * 16 + j * 4 + i;
                    float e = (r < 49) ? __expf(a2[tt][i] - mx) : 0.f;
                    ex[tt * 4 + i] = e; sum += e;
                }
            sum += __shfl_xor(sum, 16);
            sum += __shfl_xor(sum, 32);
            float inv = 1.f / sum;

            int s = rg * 224 + pxt * 16 + li;          // pixel within batch
#pragma unroll
            for (int tt = 0; tt < 4; ++tt)
#pragma unroll
                for (int i = 0; i < 4; ++i) {
                    int r = tt * 16 + j * 4 + i;
                    if (r < 49) ab[(size_t)r * HW + s] = f2h(ex[tt * 4 + i] * inv);
                }
        }
    }
}

// ================= final grouped einsum, 8 outputs/thread (r7-proven) =================
__global__ __launch_bounds__(256) void gather_kernel(
    const unsigned short* __restrict__ xpad, const unsigned short* __restrict__ attn,
    float* __restrict__ out)
{
    int tid = blockIdx.x * 256 + threadIdx.x;   // < 401408
    int plane = tid / 392;                      // b*64 + c
    int r1 = tid - plane * 392;
    int h = r1 / 7; int oct = r1 - h * 7; int w0 = oct * 8;
    int F0 = plane * HW + h * 56 + w0;

    const unsigned short* ap = attn + (size_t)(F0 >> 6) * 49;
    float a[49];
#pragma unroll
    for (int k = 0; k < 49; ++k) a[k] = h2f(ap[k]);

    const unsigned short* xp = xpad + (size_t)plane * (68 * 72) + w0;
    float o[8];
#pragma unroll
    for (int dw = 0; dw < 8; ++dw) o[dw] = 0.f;

#pragma unroll
    for (int p = 0; p < 7; ++p) {
        const unsigned short* rp = xp + (h + 2 * p) * 72;
        u16x8 v0 = *(const u16x8*)rp;
        u16x8 v1 = *(const u16x8*)(rp + 8);
        u16x8 v2 = *(const u16x8*)(rp + 16);
        float rr[20];
#pragma unroll
        for (int e = 0; e < 8; ++e) { rr[e] = h2f(v0[e]); rr[8 + e] = h2f(v1[e]); }
#pragma unroll
        for (int e = 0; e < 4; ++e) rr[16 + e] = h2f(v2[e]);
#pragma unroll
        for (int q = 0; q < 7; ++q) {
            float aq = a[p * 7 + q];
#pragma unroll
            for (int dw = 0; dw < 8; ++dw)
                o[dw] = fmaf(rr[dw + 2 * q], aq, o[dw]);
        }
    }

    f32x4 s0 = {o[0], o[1], o[2], o[3]};
    f32x4 s1 = {o[4], o[5], o[6], o[7]};
    *(f32x4*)(out + F0) = s0;
    *(f32x4*)(out + F0 + 4) = s1;
}

extern "C" void kernel_launch(void* const* d_in, const int* in_sizes, int n_in,
                              void* d_out, int out_size, void* d_ws, size_t ws_size,
                              hipStream_t stream)
{
    const float* x  = (const float*)d_in[0];
    const float* w1 = (const float*)d_in[1];
    const float* b1 = (const float*)d_in[2];
    const float* w2 = (const float*)d_in[3];
    const float* b2 = (const float*)d_in[4];
    float* out = (float*)d_out;

    unsigned short* attn = (unsigned short*)d_ws;              //  4.92 MB
    unsigned short* w1t  = attn + (size_t)16 * 49 * HW;        //  0.80 MB
    unsigned short* xpad = w1t + (size_t)2 * 49 * 128 * 32;    // 10.03 MB (total ~15.8 MB)

    prep_all<<<321, 256, 0, stream>>>(x, w1, w1t, xpad);
    conv_full<<<224, 512, 0, stream>>>(xpad, w1t, b1, w2, b2, attn);
    gather_kernel<<<1568, 256, 0, stream>>>(xpad, attn, out);
}

// Round 14
// 73.347 us; speedup vs baseline: 1.0391x; 1.0391x over previous
//
#include <hip/hip_runtime.h>
#include <hip/hip_bf16.h>

#define HW 3136            // 56*56
#define NPIX 50176         // 16*3136

typedef __attribute__((ext_vector_type(8))) _Float16 f16x8;
typedef __attribute__((ext_vector_type(4))) float f32x4;
typedef __attribute__((ext_vector_type(8))) unsigned short u16x8;

__device__ inline unsigned short f2h(float v){
    _Float16 h = (_Float16)v;
    union { _Float16 h; unsigned short u; } cv; cv.h = h; return cv.u;
}
__device__ inline float h2f(unsigned short u){
    union { unsigned short u; _Float16 h; } cv; cv.u = u; return (float)cv.h;
}

// ================= fused prep (r7-proven, unchanged) =================
// A (blocks 0..391):   x -> xg[(b*2+g)][s][32ic fp16]
// B (blocks 392..663): x -> xpad[plane][68][72] fp16, zero halo
// C (blocks 664..712): w1 -> w1t[g][tap][oc][32ic] fp16
__global__ __launch_bounds__(256) void prep_all(
    const float* __restrict__ x, const float* __restrict__ w1,
    unsigned short* __restrict__ xg, unsigned short* __restrict__ w1t,
    unsigned short* __restrict__ xpad)
{
    int bb = blockIdx.x;
    if (bb < 392) {
        int t = bb * 256 + threadIdx.x;           // < 100352
        int g = t / NPIX;
        int pix = t - g * NPIX;
        int b = pix / HW; int s = pix - b * HW;
        const float* xp = x + (size_t)b * 64 * HW + (size_t)g * 32 * HW + s;
        unsigned short* dst = xg + ((size_t)(b * 2 + g) * HW + s) * 32;
#pragma unroll
        for (int p = 0; p < 4; ++p) {
            alignas(16) unsigned short tmp[8];
#pragma unroll
            for (int e = 0; e < 8; ++e)
                tmp[e] = f2h(xp[(size_t)(p * 8 + e) * HW]);
            *(u16x8*)(dst + p * 8) = *(const u16x8*)tmp;
        }
    } else if (bb < 664) {
        int t2 = (bb - 392) * 256 + threadIdx.x;  // < 69632
        int plane = t2 / 68; int r = t2 - plane * 68;
        unsigned short* dst = xpad + ((size_t)plane * 68 + r) * 72;
        int h = r - 6;
        alignas(16) unsigned short tmp[72];
#pragma unroll
        for (int i = 0; i < 72; ++i) tmp[i] = 0;
        if (h >= 0 && h < 56) {
            const float* src = x + (size_t)plane * HW + h * 56;
#pragma unroll
            for (int wq = 0; wq < 56; ++wq) tmp[6 + wq] = f2h(src[wq]);
        }
#pragma unroll
        for (int k = 0; k < 9; ++k)
            *(u16x8*)(dst + k * 8) = *(const u16x8*)(tmp + k * 8);
    } else {
        int t = (bb - 664) * 256 + threadIdx.x;   // < 12544 = 2*49*128
        if (t < 2 * 49 * 128) {
            int g = t / (49 * 128);
            int r = t - g * 49 * 128;
            int tap = r / 128; int oc = r - tap * 128;
            unsigned short* dst = w1t + (size_t)t * 32;
            for (int ic = 0; ic < 32; ++ic)
                dst[ic] = f2h(w1[((size_t)oc * 64 + g * 32 + ic) * 49 + tap]);
        }
    }
}

// ================= conv1(full K, dual-resident halves) + conv2 + softmax =================
// grid 224 = (b16, rg14); block 512 = 8 waves; waves 0-3: g=0, waves 4-7: g=1
// each wave: 112px x 64oc (7mt x 4nt), 49 taps, no mid-loop barriers
// schedule: A dbuf, B tri-buf (distance 2); sched_barrier(0x8) = loads pinned,
// MFMA may cross -> matrix work overlaps ds/vmem issue phases
// LDS: 2 planes x 16rows x 68sites x 72B = 156672 B (1 block/CU)
#define LOADA(Abuf, tap) do {                                                 \
    const int p_ = (tap) / 7, q_ = (tap) - 7 * ((tap) / 7);                   \
    const int off_ = p_ * 9792 + q_ * 144;                                    \
    _Pragma("unroll")                                                         \
    for (int mt = 0; mt < 7; ++mt)                                            \
        Abuf[mt] = *(const f16x8*)(smem + abase[mt] + off_);                  \
    } while (0)

#define LOADB(Bbuf, tap) do {                                                 \
    const unsigned short* p_ = wb + (size_t)(tap) * 4096;                     \
    Bbuf[0] = *(const f16x8*)(p_);                                            \
    Bbuf[1] = *(const f16x8*)(p_ + 512);                                      \
    Bbuf[2] = *(const f16x8*)(p_ + 1024);                                     \
    Bbuf[3] = *(const f16x8*)(p_ + 1536);                                     \
    } while (0)

#define DOMFMA(Abuf, Bbuf) do {                                               \
    __builtin_amdgcn_s_setprio(1);                                            \
    _Pragma("unroll")                                                         \
    for (int mt = 0; mt < 7; ++mt) {                                          \
        acc[mt][0] = __builtin_amdgcn_mfma_f32_16x16x32_f16(Abuf[mt], Bbuf[0], acc[mt][0], 0, 0, 0); \
        acc[mt][1] = __builtin_amdgcn_mfma_f32_16x16x32_f16(Abuf[mt], Bbuf[1], acc[mt][1], 0, 0, 0); \
        acc[mt][2] = __builtin_amdgcn_mfma_f32_16x16x32_f16(Abuf[mt], Bbuf[2], acc[mt][2], 0, 0, 0); \
        acc[mt][3] = __builtin_amdgcn_mfma_f32_16x16x32_f16(Abuf[mt], Bbuf[3], acc[mt][3], 0, 0, 0); \
    }                                                                         \
    __builtin_amdgcn_s_setprio(0);                                            \
    } while (0)

__global__ __launch_bounds__(512, 2) void conv_full(
    const unsigned short* __restrict__ xg, const unsigned short* __restrict__ w1t,
    const float* __restrict__ b1, const float* __restrict__ w2,
    const float* __restrict__ b2, unsigned short* __restrict__ attn)
{
    __shared__ char smem[156672];                      // 2 x 78336
    unsigned short* k1sa = (unsigned short*)smem;            // [224][136] 60928 B (epilogue)
    unsigned short* w2s  = (unsigned short*)(smem + 60928);  // [64][136]  17408 B
    unsigned short* k1sb = (unsigned short*)(smem + 78336);  // [224][136] 60928 B

    const int blk = blockIdx.x;
    const int b   = blk / 14; const int rg = blk - b * 14;
    const int h0  = rg * 4;
    const int tid = threadIdx.x;
    const int lane = tid & 63, warp = tid >> 6;        // 8 waves
    const int g   = warp >> 2;                         // ic-half
    const int wm  = (warp >> 1) & 1, wn = warp & 1;
    const int oc0 = wn * 64;
    const int li  = lane & 15, j = lane >> 4;

    const unsigned short* xplane[2] = {
        xg + (size_t)(b * 2 + 0) * HW * 32,
        xg + (size_t)(b * 2 + 1) * HW * 32 };

    u16x8 zz; for (int e = 0; e < 8; ++e) zz[e] = 0;

    // ---- issue staged loads for BOTH planes (14 x 16B per thread) ----
    u16x8 sv[14];
#pragma unroll
    for (int u = 0; u < 14; ++u) {
        int i = u * 512 + tid;                         // < 7168 = 2*16*224
        int pl = i / 3584; int rem = i - pl * 3584;
        int row = rem / 224; int r2 = rem - row * 224;
        int site = r2 >> 2, chunk = r2 & 3;
        int hh = h0 - 6 + row;
        sv[u] = (hh >= 0 && hh < 56)
            ? *(const u16x8*)(xplane[pl] + ((size_t)hh * 56 + site) * 32 + chunk * 8)
            : zz;
    }

    // ---- zero all LDS (halos stay zero) ----
    {
        f32x4 zv = {0.f, 0.f, 0.f, 0.f};
#pragma unroll
        for (int u = 0; u < 20; ++u) {
            int i = u * 512 + tid;
            if (i < 9792) *(f32x4*)(smem + (size_t)i * 16) = zv;
        }
    }
    __syncthreads();

    // ---- write staged tiles (site stride 72B) ----
#pragma unroll
    for (int u = 0; u < 14; ++u) {
        int i = u * 512 + tid;
        int pl = i / 3584; int rem = i - pl * 3584;
        int row = rem / 224; int r2 = rem - row * 224;
        int site = r2 >> 2, chunk = r2 & 3;
        int hh = h0 - 6 + row;
        if (hh >= 0 && hh < 56)
            *(u16x8*)(smem + pl * 78336 + (row * 68 + 6 + site) * 72 + chunk * 16) = sv[u];
    }
    __syncthreads();

    // ---- A base addresses (fixed across all taps; include plane offset) ----
    int abase[7];
#pragma unroll
    for (int mt = 0; mt < 7; ++mt) {
        int local = wm * 112 + mt * 16 + li;           // 0..223
        int rb = local / 56; int wp = local - rb * 56;
        abase[mt] = g * 78336 + (rb * 68 + wp) * 72 + j * 16;
    }

    f32x4 acc[7][4];
#pragma unroll
    for (int mt = 0; mt < 7; ++mt)
#pragma unroll
        for (int nt = 0; nt < 4; ++nt)
#pragma unroll
            for (int c = 0; c < 4; ++c) acc[mt][nt][c] = 0.f;

    // B base: w1t[g][tap][oc][32], oc = oc0 + li (+nt*16 via imm)
    const unsigned short* wb = w1t + ((size_t)g * 49 * 128 + oc0 + li) * 32 + j * 8;

    // ---- 49-tap fully-unrolled loop; A dbuf, B tri-buf (distance 2) ----
    // sched_barrier(0x8): loads pinned to their slot, MFMA free to interleave
    {
        f16x8 A[2][7], B[3][4];
        LOADA(A[0], 0); LOADB(B[0], 0); LOADB(B[1], 1);
#pragma unroll
        for (int t = 0; t < 49; ++t) {
            if (t < 48) LOADA(A[(t + 1) & 1], t + 1);
            if (t < 47) LOADB(B[(t + 2) % 3], t + 2);
            __builtin_amdgcn_sched_barrier(0x8);
            DOMFMA(A[t & 1], B[t % 3]);
            __builtin_amdgcn_sched_barrier(0x8);
        }
    }

    // ---- issue w2 loads (after tap loop; covered by epilogue k1 writes) ----
    f32x4 wv[4];
#pragma unroll
    for (int u = 0; u < 4; ++u) {
        int idx = u * 512 + tid;                       // f32x4 index, < 1568
        wv[u] = (idx < 1568) ? *(const f32x4*)(w2 + (size_t)idx * 4)
                             : (f32x4){0.f, 0.f, 0.f, 0.f};
    }

    __syncthreads();          // all staging readers done; LDS can be overlaid

    // ---- epilogue phase A: write k1 partials + w2s ----
    // g0 waves -> k1sa (+bias); g1 waves -> k1sb (no bias)
    {
        unsigned short* kb = g ? k1sb : k1sa;
        const int pixbase = wm * 112;
#pragma unroll
        for (int nt = 0; nt < 4; ++nt) {
            int oc = oc0 + nt * 16 + li;
            float bias = g ? 0.f : b1[oc];
#pragma unroll
            for (int mt = 0; mt < 7; ++mt) {
#pragma unroll
                for (int i = 0; i < 4; ++i) {
                    int px = pixbase + mt * 16 + j * 4 + i;
                    kb[px * 136 + oc] = f2h(acc[mt][nt][i] + bias);
                }
            }
        }
    }
    // w2s [64 taps][136] fp16 (rows >=49 garbage, masked later)
#pragma unroll
    for (int u = 0; u < 4; ++u) {
        int idx = u * 512 + tid;
        if (idx < 1568) {
            int a = idx / 32; int c0 = (idx - a * 32) * 4;
            alignas(8) unsigned short t4[4];
#pragma unroll
            for (int e = 0; e < 4; ++e) t4[e] = f2h(wv[u][e]);
            *(unsigned long long*)(w2s + a * 136 + c0) = *(const unsigned long long*)t4;
        }
    }
    __syncthreads();

    // ---- conv2: L[tap][px] = w2 @ (k1a + k1b), softmax over taps, -> attn fp16 ----
    // 14 px-tiles over 8 waves: waves 0..5 take 2, waves 6,7 take 1
    const int start = (warp < 6) ? warp * 2 : 12 + (warp - 6);
    const int cnt   = (warp < 6) ? 2 : 1;
    unsigned short* ab = attn + (size_t)b * 49 * HW;

#pragma unroll
    for (int u = 0; u < 2; ++u) {
        if (u < cnt) {
            int pxt = start + u;
            f32x4 a2[4];
#pragma unroll
            for (int tt = 0; tt < 4; ++tt)
#pragma unroll
                for (int c = 0; c < 4; ++c) a2[tt][c] = 0.f;
#pragma unroll
            for (int ks = 0; ks < 4; ++ks) {
                const f16x8 ba = *(const f16x8*)(k1sa + (pxt * 16 + li) * 136 + ks * 32 + j * 8);
                const f16x8 bbv = *(const f16x8*)(k1sb + (pxt * 16 + li) * 136 + ks * 32 + j * 8);
                const f16x8 bf = ba + bbv;             // packed fp16 add
#pragma unroll
                for (int tt = 0; tt < 4; ++tt) {
                    const f16x8 af = *(const f16x8*)(w2s + (tt * 16 + li) * 136 + ks * 32 + j * 8);
                    a2[tt] = __builtin_amdgcn_mfma_f32_16x16x32_f16(af, bf, a2[tt], 0, 0, 0);
                }
            }
            // softmax over taps (rows) for pixel col li
            float mx = -3e38f;
#pragma unroll
            for (int tt = 0; tt < 4; ++tt)
#pragma unroll
                for (int i = 0; i < 4; ++i) {
                    int r = tt * 16 + j * 4 + i;
                    float v = a2[tt][i] + ((r < 49) ? b2[r] : 0.f);
                    a2[tt][i] = v;
                    if (r < 49) mx = fmaxf(mx, v);
                }
            mx = fmaxf(mx, __shfl_xor(mx, 16));
            mx = fmaxf(mx, __shfl_xor(mx, 32));
            float sum = 0.f; float ex[16];
#pragma unroll
            for (int tt = 0; tt < 4; ++tt)
#pragma unroll
                for (int i = 0; i < 4; ++i) {
                    int r = tt * 16 + j * 4 + i;
                    float e = (r < 49) ? __expf(a2[tt][i] - mx) : 0.f;
                    ex[tt * 4 + i] = e; sum += e;
                }
            sum += __shfl_xor(sum, 16);
            sum += __shfl_xor(sum, 32);
            float inv = 1.f / sum;

            int s = rg * 224 + pxt * 16 + li;          // pixel within batch
#pragma unroll
            for (int tt = 0; tt < 4; ++tt)
#pragma unroll
                for (int i = 0; i < 4; ++i) {
                    int r = tt * 16 + j * 4 + i;
                    if (r < 49) ab[(size_t)r * HW + s] = f2h(ex[tt * 4 + i] * inv);
                }
        }
    }
}

// ================= final grouped einsum, 8 outputs/thread (r7-proven) =================
__global__ __launch_bounds__(256) void gather_kernel(
    const unsigned short* __restrict__ xpad, const unsigned short* __restrict__ attn,
    float* __restrict__ out)
{
    int tid = blockIdx.x * 256 + threadIdx.x;   // < 401408
    int plane = tid / 392;                      // b*64 + c
    int r1 = tid - plane * 392;
    int h = r1 / 7; int oct = r1 - h * 7; int w0 = oct * 8;
    int F0 = plane * HW + h * 56 + w0;

    const unsigned short* ap = attn + (size_t)(F0 >> 6) * 49;
    float a[49];
#pragma unroll
    for (int k = 0; k < 49; ++k) a[k] = h2f(ap[k]);

    const unsigned short* xp = xpad + (size_t)plane * (68 * 72) + w0;
    float o[8];
#pragma unroll
    for (int dw = 0; dw < 8; ++dw) o[dw] = 0.f;

#pragma unroll
    for (int p = 0; p < 7; ++p) {
        const unsigned short* rp = xp + (h + 2 * p) * 72;
        u16x8 v0 = *(const u16x8*)rp;
        u16x8 v1 = *(const u16x8*)(rp + 8);
        u16x8 v2 = *(const u16x8*)(rp + 16);
        float rr[20];
#pragma unroll
        for (int e = 0; e < 8; ++e) { rr[e] = h2f(v0[e]); rr[8 + e] = h2f(v1[e]); }
#pragma unroll
        for (int e = 0; e < 4; ++e) rr[16 + e] = h2f(v2[e]);
#pragma unroll
        for (int q = 0; q < 7; ++q) {
            float aq = a[p * 7 + q];
#pragma unroll
            for (int dw = 0; dw < 8; ++dw)
                o[dw] = fmaf(rr[dw + 2 * q], aq, o[dw]);
        }
    }

    f32x4 s0 = {o[0], o[1], o[2], o[3]};
    f32x4 s1 = {o[4], o[5], o[6], o[7]};
    *(f32x4*)(out + F0) = s0;
    *(f32x4*)(out + F0 + 4) = s1;
}

extern "C" void kernel_launch(void* const* d_in, const int* in_sizes, int n_in,
                              void* d_out, int out_size, void* d_ws, size_t ws_size,
                              hipStream_t stream)
{
    const float* x  = (const float*)d_in[0];
    const float* w1 = (const float*)d_in[1];
    const float* b1 = (const float*)d_in[2];
    const float* w2 = (const float*)d_in[3];
    const float* b2 = (const float*)d_in[4];
    float* out = (float*)d_out;

    unsigned short* attn = (unsigned short*)d_ws;              //  4.92 MB
    unsigned short* xg   = attn + (size_t)16 * 49 * HW;        //  6.42 MB
    unsigned short* w1t  = xg + (size_t)16 * 2 * HW * 32;      //  0.80 MB
    unsigned short* xpad = w1t + (size_t)2 * 49 * 128 * 32;    // 10.03 MB (total ~22.2 MB)

    prep_all<<<713, 256, 0, stream>>>(x, w1, xg, w1t, xpad);
    conv_full<<<224, 512, 0, stream>>>(xg, w1t, b1, w2, b2, attn);
    gather_kernel<<<1568, 256, 0, stream>>>(xpad, attn, out);
}

// Round 15
// 69.760 us; speedup vs baseline: 1.0925x; 1.0514x over previous
//
#include <hip/hip_runtime.h>
#include <hip/hip_bf16.h>

#define HW 3136            // 56*56
#define NPIX 50176         // 16*3136

typedef __attribute__((ext_vector_type(8))) _Float16 f16x8;
typedef __attribute__((ext_vector_type(4))) float f32x4;
typedef __attribute__((ext_vector_type(8))) unsigned short u16x8;

__device__ inline unsigned short f2h(float v){
    _Float16 h = (_Float16)v;
    union { _Float16 h; unsigned short u; } cv; cv.h = h; return cv.u;
}
__device__ inline float h2f(unsigned short u){
    union { unsigned short u; _Float16 h; } cv; cv.u = u; return (float)cv.h;
}

// ================= fused prep =================
// A (blocks 0..391):   x -> xg[(b*2+g)][s][32ic fp16]
// B (blocks 392..663): x -> xpad[plane][68][72] fp16, zero halo
// C (blocks 664..859): w1 -> w1t[g][p][oc][q][j][8ic] fp16 (row-loop imm addressing)
__global__ __launch_bounds__(256) void prep_all(
    const float* __restrict__ x, const float* __restrict__ w1,
    unsigned short* __restrict__ xg, unsigned short* __restrict__ w1t,
    unsigned short* __restrict__ xpad)
{
    int bb = blockIdx.x;
    if (bb < 392) {
        int t = bb * 256 + threadIdx.x;           // < 100352
        int g = t / NPIX;
        int pix = t - g * NPIX;
        int b = pix / HW; int s = pix - b * HW;
        const float* xp = x + (size_t)b * 64 * HW + (size_t)g * 32 * HW + s;
        unsigned short* dst = xg + ((size_t)(b * 2 + g) * HW + s) * 32;
#pragma unroll
        for (int p = 0; p < 4; ++p) {
            alignas(16) unsigned short tmp[8];
#pragma unroll
            for (int e = 0; e < 8; ++e)
                tmp[e] = f2h(xp[(size_t)(p * 8 + e) * HW]);
            *(u16x8*)(dst + p * 8) = *(const u16x8*)tmp;
        }
    } else if (bb < 664) {
        int t2 = (bb - 392) * 256 + threadIdx.x;  // < 69632
        int plane = t2 / 68; int r = t2 - plane * 68;
        unsigned short* dst = xpad + ((size_t)plane * 68 + r) * 72;
        int h = r - 6;
        alignas(16) unsigned short tmp[72];
#pragma unroll
        for (int i = 0; i < 72; ++i) tmp[i] = 0;
        if (h >= 0 && h < 56) {
            const float* src = x + (size_t)plane * HW + h * 56;
#pragma unroll
            for (int wq = 0; wq < 56; ++wq) tmp[6 + wq] = f2h(src[wq]);
        }
#pragma unroll
        for (int k = 0; k < 9; ++k)
            *(u16x8*)(dst + k * 8) = *(const u16x8*)(tmp + k * 8);
    } else {
        int t = (bb - 664) * 256 + threadIdx.x;   // < 50176 = 2*7*128*7*4
        int g = t / 25088;
        int r = t - g * 25088;                    // p*3584 + oc*28 + q*4 + j
        int p = r / 3584; int r2 = r - p * 3584;
        int oc = r2 / 28; int r3 = r2 - oc * 28;
        int q = r3 >> 2; int j = r3 & 3;
        unsigned short* dst = w1t + (size_t)t * 8;
        alignas(16) unsigned short tmp[8];
#pragma unroll
        for (int e = 0; e < 8; ++e)
            tmp[e] = f2h(w1[((size_t)(oc * 64 + g * 32 + j * 8 + e)) * 49 + p * 7 + q]);
        *(u16x8*)dst = *(const u16x8*)tmp;
    }
}

// ================= conv1(full K, dual-resident halves) + conv2 + softmax =================
// grid 224 = (b16, rg14); block 512 = 8 waves; waves 0-3: g=0, waves 4-7: g=1
// tap loop = p-row loop (unroll 1, ~2.8KB body -> I$-resident) x 7 imm-addressed taps
// A dbuf, B tri-buf, r9 sched_barrier pins + setprio; cross-row prefetch at slots 5/6
// LDS: 2 planes x 16rows x 68sites x 72B = 156672 B (1 block/CU)
#define SB0 __builtin_amdgcn_sched_barrier(0)

#define LOADA(Abuf, immB) do {                                                \
    _Pragma("unroll")                                                         \
    for (int mt = 0; mt < 7; ++mt)                                            \
        Abuf[mt] = *(const f16x8*)(smem + abase[mt] + (immB));                \
    } while (0)

#define LOADB(Bbuf, immS) do {                                                \
    Bbuf[0] = *(const f16x8*)(wb0 + (immS));                                  \
    Bbuf[1] = *(const f16x8*)(wb1 + (immS));                                  \
    Bbuf[2] = *(const f16x8*)(wb2 + (immS));                                  \
    Bbuf[3] = *(const f16x8*)(wb3 + (immS));                                  \
    } while (0)

#define DOMFMA(Abuf, Bbuf) do {                                               \
    __builtin_amdgcn_s_setprio(1);                                            \
    _Pragma("unroll")                                                         \
    for (int mt = 0; mt < 7; ++mt) {                                          \
        acc[mt][0] = __builtin_amdgcn_mfma_f32_16x16x32_f16(Abuf[mt], Bbuf[0], acc[mt][0], 0, 0, 0); \
        acc[mt][1] = __builtin_amdgcn_mfma_f32_16x16x32_f16(Abuf[mt], Bbuf[1], acc[mt][1], 0, 0, 0); \
        acc[mt][2] = __builtin_amdgcn_mfma_f32_16x16x32_f16(Abuf[mt], Bbuf[2], acc[mt][2], 0, 0, 0); \
        acc[mt][3] = __builtin_amdgcn_mfma_f32_16x16x32_f16(Abuf[mt], Bbuf[3], acc[mt][3], 0, 0, 0); \
    }                                                                         \
    __builtin_amdgcn_s_setprio(0);                                            \
    } while (0)

__global__ __launch_bounds__(512, 2) void conv_full(
    const unsigned short* __restrict__ xg, const unsigned short* __restrict__ w1t,
    const float* __restrict__ b1, const float* __restrict__ w2,
    const float* __restrict__ b2, unsigned short* __restrict__ attn)
{
    __shared__ char smem[156672];                      // 2 x 78336
    unsigned short* k1sa = (unsigned short*)smem;            // [224][136] 60928 B (epilogue)
    unsigned short* w2s  = (unsigned short*)(smem + 60928);  // [64][136]  17408 B
    unsigned short* k1sb = (unsigned short*)(smem + 78336);  // [224][136] 60928 B

    const int blk = blockIdx.x;
    const int b   = blk / 14; const int rg = blk - b * 14;
    const int h0  = rg * 4;
    const int tid = threadIdx.x;
    const int lane = tid & 63, warp = tid >> 6;        // 8 waves
    const int g   = warp >> 2;                         // ic-half
    const int wm  = (warp >> 1) & 1, wn = warp & 1;
    const int oc0 = wn * 64;
    const int li  = lane & 15, j = lane >> 4;

    const unsigned short* xplane[2] = {
        xg + (size_t)(b * 2 + 0) * HW * 32,
        xg + (size_t)(b * 2 + 1) * HW * 32 };

    u16x8 zz; for (int e = 0; e < 8; ++e) zz[e] = 0;

    // ---- issue staged loads for BOTH planes (14 x 16B per thread) ----
    u16x8 sv[14];
#pragma unroll
    for (int u = 0; u < 14; ++u) {
        int i = u * 512 + tid;                         // < 7168 = 2*16*224
        int pl = i / 3584; int rem = i - pl * 3584;
        int row = rem / 224; int r2 = rem - row * 224;
        int site = r2 >> 2, chunk = r2 & 3;
        int hh = h0 - 6 + row;
        sv[u] = (hh >= 0 && hh < 56)
            ? *(const u16x8*)(xplane[pl] + ((size_t)hh * 56 + site) * 32 + chunk * 8)
            : zz;
    }

    // ---- zero all LDS (halos stay zero) ----
    {
        f32x4 zv = {0.f, 0.f, 0.f, 0.f};
#pragma unroll
        for (int u = 0; u < 20; ++u) {
            int i = u * 512 + tid;
            if (i < 9792) *(f32x4*)(smem + (size_t)i * 16) = zv;
        }
    }
    __syncthreads();

    // ---- write staged tiles (site stride 72B) ----
#pragma unroll
    for (int u = 0; u < 14; ++u) {
        int i = u * 512 + tid;
        int pl = i / 3584; int rem = i - pl * 3584;
        int row = rem / 224; int r2 = rem - row * 224;
        int site = r2 >> 2, chunk = r2 & 3;
        int hh = h0 - 6 + row;
        if (hh >= 0 && hh < 56)
            *(u16x8*)(smem + pl * 78336 + (row * 68 + 6 + site) * 72 + chunk * 16) = sv[u];
    }
    __syncthreads();

    // ---- A base addresses (rolling, +9792 per p-row) ----
    int abase[7];
#pragma unroll
    for (int mt = 0; mt < 7; ++mt) {
        int local = wm * 112 + mt * 16 + li;           // 0..223
        int rb = local / 56; int wp = local - rb * 56;
        abase[mt] = g * 78336 + (rb * 68 + wp) * 72 + j * 16;
    }

    f32x4 acc[7][4];
#pragma unroll
    for (int mt = 0; mt < 7; ++mt)
#pragma unroll
        for (int nt = 0; nt < 4; ++nt)
#pragma unroll
            for (int c = 0; c < 4; ++c) acc[mt][nt][c] = 0.f;

    // B rolling pointers: w1t[g][p][oc][q][j][8]; oc row stride 224 shorts,
    // q imm stride 32 shorts, p advance 128*224 = 28672 shorts
    const unsigned short* wb0 = w1t + ((size_t)(g * 7) * 128 + oc0 + li) * 224 + j * 8;
    const unsigned short* wb1 = wb0 + (size_t)16 * 224;
    const unsigned short* wb2 = wb0 + (size_t)32 * 224;
    const unsigned short* wb3 = wb0 + (size_t)48 * 224;

    // ---- p-row loop: 7 imm-addressed taps per row, I$-resident body ----
    {
        f16x8 A0[7], A1[7], B0[4], B1[4], B2[4];
        LOADA(A0, 0); LOADB(B0, 0); LOADB(B1, 32);
#pragma unroll 1
        for (int p = 0; p < 7; ++p) {
            // slot 0 (tap q0)
            LOADA(A1, 144); LOADB(B2, 64);
            SB0; DOMFMA(A0, B0); SB0;
            // slot 1 (q1)
            LOADA(A0, 288); LOADB(B0, 96);
            SB0; DOMFMA(A1, B1); SB0;
            // slot 2 (q2)
            LOADA(A1, 432); LOADB(B1, 128);
            SB0; DOMFMA(A0, B2); SB0;
            // slot 3 (q3)
            LOADA(A0, 576); LOADB(B2, 160);
            SB0; DOMFMA(A1, B0); SB0;
            // slot 4 (q4)
            LOADA(A1, 720); LOADB(B0, 192);
            SB0; DOMFMA(A0, B1); SB0;
            // slot 5 (q5): load A(q6); advance B pointers for next row
            LOADA(A0, 864);
            wb0 += 28672; wb1 += 28672; wb2 += 28672; wb3 += 28672;
            SB0; DOMFMA(A1, B2); SB0;
            // slot 6 (q6): advance A bases; MFMA; then next-row prefetch
#pragma unroll
            for (int mt = 0; mt < 7; ++mt) abase[mt] += 9792;
            DOMFMA(A0, B0);
            SB0;
            if (p < 6) {
                LOADA(A0, 0);          // next row q0 (abase already advanced)
                LOADB(B0, 0);          // next row q0
                LOADB(B1, 32);         // next row q1
            }
            SB0;
        }
    }

    // ---- issue w2 loads (after tap loop; covered by epilogue k1 writes) ----
    f32x4 wv[4];
#pragma unroll
    for (int u = 0; u < 4; ++u) {
        int idx = u * 512 + tid;                       // f32x4 index, < 1568
        wv[u] = (idx < 1568) ? *(const f32x4*)(w2 + (size_t)idx * 4)
                             : (f32x4){0.f, 0.f, 0.f, 0.f};
    }

    __syncthreads();          // all staging readers done; LDS can be overlaid

    // ---- epilogue phase A: write k1 partials + w2s ----
    {
        unsigned short* kb = g ? k1sb : k1sa;
        const int pixbase = wm * 112;
#pragma unroll
        for (int nt = 0; nt < 4; ++nt) {
            int oc = oc0 + nt * 16 + li;
            float bias = g ? 0.f : b1[oc];
#pragma unroll
            for (int mt = 0; mt < 7; ++mt) {
#pragma unroll
                for (int i = 0; i < 4; ++i) {
                    int px = pixbase + mt * 16 + j * 4 + i;
                    kb[px * 136 + oc] = f2h(acc[mt][nt][i] + bias);
                }
            }
        }
    }
    // w2s [64 taps][136] fp16 (rows >=49 garbage, masked later)
#pragma unroll
    for (int u = 0; u < 4; ++u) {
        int idx = u * 512 + tid;
        if (idx < 1568) {
            int a = idx / 32; int c0 = (idx - a * 32) * 4;
            alignas(8) unsigned short t4[4];
#pragma unroll
            for (int e = 0; e < 4; ++e) t4[e] = f2h(wv[u][e]);
            *(unsigned long long*)(w2s + a * 136 + c0) = *(const unsigned long long*)t4;
        }
    }
    __syncthreads();

    // ---- conv2: L[tap][px] = w2 @ (k1a + k1b), softmax over taps, -> attn fp16 ----
    const int start = (warp < 6) ? warp * 2 : 12 + (warp - 6);
    const int cnt   = (warp < 6) ? 2 : 1;
    unsigned short* ab = attn + (size_t)b * 49 * HW;

#pragma unroll
    for (int u = 0; u < 2; ++u) {
        if (u < cnt) {
            int pxt = start + u;
            f32x4 a2[4];
#pragma unroll
            for (int tt = 0; tt < 4; ++tt)
#pragma unroll
                for (int c = 0; c < 4; ++c) a2[tt][c] = 0.f;
#pragma unroll
            for (int ks = 0; ks < 4; ++ks) {
                const f16x8 ba = *(const f16x8*)(k1sa + (pxt * 16 + li) * 136 + ks * 32 + j * 8);
                const f16x8 bbv = *(const f16x8*)(k1sb + (pxt * 16 + li) * 136 + ks * 32 + j * 8);
                const f16x8 bf = ba + bbv;             // packed fp16 add
#pragma unroll
                for (int tt = 0; tt < 4; ++tt) {
                    const f16x8 af = *(const f16x8*)(w2s + (tt * 16 + li) * 136 + ks * 32 + j * 8);
                    a2[tt] = __builtin_amdgcn_mfma_f32_16x16x32_f16(af, bf, a2[tt], 0, 0, 0);
                }
            }
            float mx = -3e38f;
#pragma unroll
            for (int tt = 0; tt < 4; ++tt)
#pragma unroll
                for (int i = 0; i < 4; ++i) {
                    int r = tt * 16 + j * 4 + i;
                    float v = a2[tt][i] + ((r < 49) ? b2[r] : 0.f);
                    a2[tt][i] = v;
                    if (r < 49) mx = fmaxf(mx, v);
                }
            mx = fmaxf(mx, __shfl_xor(mx, 16));
            mx = fmaxf(mx, __shfl_xor(mx, 32));
            float sum = 0.f; float ex[16];
#pragma unroll
            for (int tt = 0; tt < 4; ++tt)
#pragma unroll
                for (int i = 0; i < 4; ++i) {
                    int r = tt * 16 + j * 4 + i;
                    float e = (r < 49) ? __expf(a2[tt][i] - mx) : 0.f;
                    ex[tt * 4 + i] = e; sum += e;
                }
            sum += __shfl_xor(sum, 16);
            sum += __shfl_xor(sum, 32);
            float inv = 1.f / sum;

            int s = rg * 224 + pxt * 16 + li;          // pixel within batch
#pragma unroll
            for (int tt = 0; tt < 4; ++tt)
#pragma unroll
                for (int i = 0; i < 4; ++i) {
                    int r = tt * 16 + j * 4 + i;
                    if (r < 49) ab[(size_t)r * HW + s] = f2h(ex[tt * 4 + i] * inv);
                }
        }
    }
}

// ================= final grouped einsum, 8 outputs/thread (r7-proven) =================
__global__ __launch_bounds__(256) void gather_kernel(
    const unsigned short* __restrict__ xpad, const unsigned short* __restrict__ attn,
    float* __restrict__ out)
{
    int tid = blockIdx.x * 256 + threadIdx.x;   // < 401408
    int plane = tid / 392;                      // b*64 + c
    int r1 = tid - plane * 392;
    int h = r1 / 7; int oct = r1 - h * 7; int w0 = oct * 8;
    int F0 = plane * HW + h * 56 + w0;

    const unsigned short* ap = attn + (size_t)(F0 >> 6) * 49;
    float a[49];
#pragma unroll
    for (int k = 0; k < 49; ++k) a[k] = h2f(ap[k]);

    const unsigned short* xp = xpad + (size_t)plane * (68 * 72) + w0;
    float o[8];
#pragma unroll
    for (int dw = 0; dw < 8; ++dw) o[dw] = 0.f;

#pragma unroll
    for (int p = 0; p < 7; ++p) {
        const unsigned short* rp = xp + (h + 2 * p) * 72;
        u16x8 v0 = *(const u16x8*)rp;
        u16x8 v1 = *(const u16x8*)(rp + 8);
        u16x8 v2 = *(const u16x8*)(rp + 16);
        float rr[20];
#pragma unroll
        for (int e = 0; e < 8; ++e) { rr[e] = h2f(v0[e]); rr[8 + e] = h2f(v1[e]); }
#pragma unroll
        for (int e = 0; e < 4; ++e) rr[16 + e] = h2f(v2[e]);
#pragma unroll
        for (int q = 0; q < 7; ++q) {
            float aq = a[p * 7 + q];
#pragma unroll
            for (int dw = 0; dw < 8; ++dw)
                o[dw] = fmaf(rr[dw + 2 * q], aq, o[dw]);
        }
    }

    f32x4 s0 = {o[0], o[1], o[2], o[3]};
    f32x4 s1 = {o[4], o[5], o[6], o[7]};
    *(f32x4*)(out + F0) = s0;
    *(f32x4*)(out + F0 + 4) = s1;
}

extern "C" void kernel_launch(void* const* d_in, const int* in_sizes, int n_in,
                              void* d_out, int out_size, void* d_ws, size_t ws_size,
                              hipStream_t stream)
{
    const float* x  = (const float*)d_in[0];
    const float* w1 = (const float*)d_in[1];
    const float* b1 = (const float*)d_in[2];
    const float* w2 = (const float*)d_in[3];
    const float* b2 = (const float*)d_in[4];
    float* out = (float*)d_out;

    unsigned short* attn = (unsigned short*)d_ws;              //  4.92 MB
    unsigned short* xg   = attn + (size_t)16 * 49 * HW;        //  6.42 MB
    unsigned short* w1t  = xg + (size_t)16 * 2 * HW * 32;      //  0.80 MB
    unsigned short* xpad = w1t + (size_t)2 * 7 * 128 * 28 * 8; // 10.03 MB (total ~22.2 MB)

    prep_all<<<860, 256, 0, stream>>>(x, w1, xg, w1t, xpad);
    conv_full<<<224, 512, 0, stream>>>(xg, w1t, b1, w2, b2, attn);
    gather_kernel<<<1568, 256, 0, stream>>>(xpad, attn, out);
}

// Round 16
// 65.476 us; speedup vs baseline: 1.1640x; 1.0654x over previous
//
#include <hip/hip_runtime.h>
#include <hip/hip_bf16.h>

#define HW 3136            // 56*56
#define NPIX 50176         // 16*3136

typedef __attribute__((ext_vector_type(8))) _Float16 f16x8;
typedef __attribute__((ext_vector_type(4))) float f32x4;
typedef __attribute__((ext_vector_type(8))) unsigned short u16x8;

__device__ inline unsigned short f2h(float v){
    _Float16 h = (_Float16)v;
    union { _Float16 h; unsigned short u; } cv; cv.h = h; return cv.u;
}
__device__ inline float h2f(unsigned short u){
    union { unsigned short u; _Float16 h; } cv; cv.u = u; return (float)cv.h;
}

// ================= fused prep =================
// A (blocks 0..391):   x -> xg[(b*2+g)][s][32ic fp16]
// B (blocks 392..663): x -> xpad[plane][68][72] fp16, zero halo
// C (blocks 664..859): w1 -> w1t[g][tap][oc][32ic] fp16  (parallel: thread per octet)
__global__ __launch_bounds__(256) void prep_all(
    const float* __restrict__ x, const float* __restrict__ w1,
    unsigned short* __restrict__ xg, unsigned short* __restrict__ w1t,
    unsigned short* __restrict__ xpad)
{
    int bb = blockIdx.x;
    if (bb < 392) {
        int t = bb * 256 + threadIdx.x;           // < 100352
        int g = t / NPIX;
        int pix = t - g * NPIX;
        int b = pix / HW; int s = pix - b * HW;
        const float* xp = x + (size_t)b * 64 * HW + (size_t)g * 32 * HW + s;
        unsigned short* dst = xg + ((size_t)(b * 2 + g) * HW + s) * 32;
#pragma unroll
        for (int p = 0; p < 4; ++p) {
            alignas(16) unsigned short tmp[8];
#pragma unroll
            for (int e = 0; e < 8; ++e)
                tmp[e] = f2h(xp[(size_t)(p * 8 + e) * HW]);
            *(u16x8*)(dst + p * 8) = *(const u16x8*)tmp;
        }
    } else if (bb < 664) {
        int t2 = (bb - 392) * 256 + threadIdx.x;  // < 69632
        int plane = t2 / 68; int r = t2 - plane * 68;
        unsigned short* dst = xpad + ((size_t)plane * 68 + r) * 72;
        int h = r - 6;
        alignas(16) unsigned short tmp[72];
#pragma unroll
        for (int i = 0; i < 72; ++i) tmp[i] = 0;
        if (h >= 0 && h < 56) {
            const float* src = x + (size_t)plane * HW + h * 56;
#pragma unroll
            for (int wq = 0; wq < 56; ++wq) tmp[6 + wq] = f2h(src[wq]);
        }
#pragma unroll
        for (int k = 0; k < 9; ++k)
            *(u16x8*)(dst + k * 8) = *(const u16x8*)(tmp + k * 8);
    } else {
        int t = (bb - 664) * 256 + threadIdx.x;   // < 50176 = 2*49*128*4
        int g = t / 25088;
        int r = t - g * 25088;                    // tap*512 + oc*4 + jo
        int tap = r / 512; int r2 = r - tap * 512;
        int oc = r2 >> 2; int jo = r2 & 3;
        unsigned short* dst = w1t + ((size_t)(g * 49 + tap) * 128 + oc) * 32 + jo * 8;
        alignas(16) unsigned short tmp[8];
#pragma unroll
        for (int e = 0; e < 8; ++e)
            tmp[e] = f2h(w1[((size_t)(oc * 64 + g * 32 + jo * 8 + e)) * 49 + tap]);
        *(u16x8*)dst = *(const u16x8*)tmp;
    }
}

// ================= conv1(full K, dual-resident halves) + conv2 + softmax =================
// grid 224 = (b16, rg14); block 512 = 8 waves; waves 0-3: g=0, waves 4-7: g=1
// each wave: 112px x 64oc (7mt x 4nt), 49 taps, no mid-loop barriers
// best-measured schedule (r8): A/B 1-tap double buffer, sched_barrier(0) pins + setprio
// LDS: 2 planes x 16rows x 68sites x 72B = 156672 B (1 block/CU)
#define LOADA(Abuf, tap) do {                                                 \
    const int p_ = (tap) / 7, q_ = (tap) - 7 * ((tap) / 7);                   \
    const int off_ = p_ * 9792 + q_ * 144;                                    \
    _Pragma("unroll")                                                         \
    for (int mt = 0; mt < 7; ++mt)                                            \
        Abuf[mt] = *(const f16x8*)(smem + abase[mt] + off_);                  \
    } while (0)

#define LOADB(Bbuf, tap) do {                                                 \
    const unsigned short* p_ = wb + (size_t)(tap) * 4096;                     \
    Bbuf[0] = *(const f16x8*)(p_);                                            \
    Bbuf[1] = *(const f16x8*)(p_ + 512);                                      \
    Bbuf[2] = *(const f16x8*)(p_ + 1024);                                    \
    Bbuf[3] = *(const f16x8*)(p_ + 1536);                                    \
    } while (0)

#define DOMFMA(Abuf, Bbuf) do {                                               \
    __builtin_amdgcn_s_setprio(1);                                            \
    _Pragma("unroll")                                                         \
    for (int mt = 0; mt < 7; ++mt) {                                          \
        acc[mt][0] = __builtin_amdgcn_mfma_f32_16x16x32_f16(Abuf[mt], Bbuf[0], acc[mt][0], 0, 0, 0); \
        acc[mt][1] = __builtin_amdgcn_mfma_f32_16x16x32_f16(Abuf[mt], Bbuf[1], acc[mt][1], 0, 0, 0); \
        acc[mt][2] = __builtin_amdgcn_mfma_f32_16x16x32_f16(Abuf[mt], Bbuf[2], acc[mt][2], 0, 0, 0); \
        acc[mt][3] = __builtin_amdgcn_mfma_f32_16x16x32_f16(Abuf[mt], Bbuf[3], acc[mt][3], 0, 0, 0); \
    }                                                                         \
    __builtin_amdgcn_s_setprio(0);                                            \
    } while (0)

__global__ __launch_bounds__(512, 2) void conv_full(
    const unsigned short* __restrict__ xg, const unsigned short* __restrict__ w1t,
    const float* __restrict__ b1, const float* __restrict__ w2,
    const float* __restrict__ b2, unsigned short* __restrict__ attn)
{
    __shared__ char smem[156672];                      // 2 x 78336
    unsigned short* k1sa = (unsigned short*)smem;            // [224][136] 60928 B (epilogue)
    unsigned short* w2s  = (unsigned short*)(smem + 60928);  // [64][136]  17408 B
    unsigned short* k1sb = (unsigned short*)(smem + 78336);  // [224][136] 60928 B

    const int blk = blockIdx.x;
    const int b   = blk / 14; const int rg = blk - b * 14;
    const int h0  = rg * 4;
    const int tid = threadIdx.x;
    const int lane = tid & 63, warp = tid >> 6;        // 8 waves
    const int g   = warp >> 2;                         // ic-half
    const int wm  = (warp >> 1) & 1, wn = warp & 1;
    const int oc0 = wn * 64;
    const int li  = lane & 15, j = lane >> 4;

    const unsigned short* xplane[2] = {
        xg + (size_t)(b * 2 + 0) * HW * 32,
        xg + (size_t)(b * 2 + 1) * HW * 32 };

    u16x8 zz; for (int e = 0; e < 8; ++e) zz[e] = 0;

    // ---- issue staged loads for BOTH planes (14 x 16B per thread) ----
    u16x8 sv[14];
#pragma unroll
    for (int u = 0; u < 14; ++u) {
        int i = u * 512 + tid;                         // < 7168 = 2*16*224
        int pl = i / 3584; int rem = i - pl * 3584;
        int row = rem / 224; int r2 = rem - row * 224;
        int site = r2 >> 2, chunk = r2 & 3;
        int hh = h0 - 6 + row;
        sv[u] = (hh >= 0 && hh < 56)
            ? *(const u16x8*)(xplane[pl] + ((size_t)hh * 56 + site) * 32 + chunk * 8)
            : zz;
    }

    // ---- zero all LDS (halos stay zero) ----
    {
        f32x4 zv = {0.f, 0.f, 0.f, 0.f};
#pragma unroll
        for (int u = 0; u < 20; ++u) {
            int i = u * 512 + tid;
            if (i < 9792) *(f32x4*)(smem + (size_t)i * 16) = zv;
        }
    }
    __syncthreads();

    // ---- write staged tiles (site stride 72B) ----
#pragma unroll
    for (int u = 0; u < 14; ++u) {
        int i = u * 512 + tid;
        int pl = i / 3584; int rem = i - pl * 3584;
        int row = rem / 224; int r2 = rem - row * 224;
        int site = r2 >> 2, chunk = r2 & 3;
        int hh = h0 - 6 + row;
        if (hh >= 0 && hh < 56)
            *(u16x8*)(smem + pl * 78336 + (row * 68 + 6 + site) * 72 + chunk * 16) = sv[u];
    }

    // ---- issue w2 loads (latency hidden under tap loop) ----
    f32x4 wv[4];
#pragma unroll
    for (int u = 0; u < 4; ++u) {
        int idx = u * 512 + tid;                       // f32x4 index, < 1568
        wv[u] = (idx < 1568) ? *(const f32x4*)(w2 + (size_t)idx * 4)
                             : (f32x4){0.f, 0.f, 0.f, 0.f};
    }
    __syncthreads();

    // ---- A base addresses (fixed across all taps; include plane offset) ----
    int abase[7];
#pragma unroll
    for (int mt = 0; mt < 7; ++mt) {
        int local = wm * 112 + mt * 16 + li;           // 0..223
        int rb = local / 56; int wp = local - rb * 56;
        abase[mt] = g * 78336 + (rb * 68 + wp) * 72 + j * 16;
    }

    f32x4 acc[7][4];
#pragma unroll
    for (int mt = 0; mt < 7; ++mt)
#pragma unroll
        for (int nt = 0; nt < 4; ++nt)
#pragma unroll
            for (int c = 0; c < 4; ++c) acc[mt][nt][c] = 0.f;

    // B base: w1t[g][tap][oc][32], oc = oc0 + li (+nt*16 via imm)
    const unsigned short* wb = w1t + ((size_t)g * 49 * 128 + oc0 + li) * 32 + j * 8;

    // ---- 49-tap fully-unrolled loop, 1-tap double buffer, pinned schedule ----
    {
        f16x8 A0[7], A1[7], B0[4], B1[4];
        LOADA(A0, 0); LOADB(B0, 0);
#pragma unroll
        for (int th = 0; th < 24; ++th) {
            LOADA(A1, 2 * th + 1); LOADB(B1, 2 * th + 1);
            __builtin_amdgcn_sched_barrier(0);
            DOMFMA(A0, B0);
            __builtin_amdgcn_sched_barrier(0);
            LOADA(A0, 2 * th + 2); LOADB(B0, 2 * th + 2);
            __builtin_amdgcn_sched_barrier(0);
            DOMFMA(A1, B1);
            __builtin_amdgcn_sched_barrier(0);
        }
        DOMFMA(A0, B0);                                // tap 48
    }

    __syncthreads();          // all staging readers done; LDS can be overlaid

    // ---- epilogue phase A: write k1 partials + w2s ----
    // g0 waves -> k1sa (+bias); g1 waves -> k1sb (no bias)
    {
        unsigned short* kb = g ? k1sb : k1sa;
        const int pixbase = wm * 112;
#pragma unroll
        for (int nt = 0; nt < 4; ++nt) {
            int oc = oc0 + nt * 16 + li;
            float bias = g ? 0.f : b1[oc];
#pragma unroll
            for (int mt = 0; mt < 7; ++mt) {
#pragma unroll
                for (int i = 0; i < 4; ++i) {
                    int px = pixbase + mt * 16 + j * 4 + i;
                    kb[px * 136 + oc] = f2h(acc[mt][nt][i] + bias);
                }
            }
        }
    }
    // w2s [64 taps][136] fp16 (rows >=49 garbage, masked later)
#pragma unroll
    for (int u = 0; u < 4; ++u) {
        int idx = u * 512 + tid;
        if (idx < 1568) {
            int a = idx / 32; int c0 = (idx - a * 32) * 4;
            alignas(8) unsigned short t4[4];
#pragma unroll
            for (int e = 0; e < 4; ++e) t4[e] = f2h(wv[u][e]);
            *(unsigned long long*)(w2s + a * 136 + c0) = *(const unsigned long long*)t4;
        }
    }
    __syncthreads();

    // ---- conv2: L[tap][px] = w2 @ (k1a + k1b), softmax over taps, -> attn fp16 ----
    // 14 px-tiles over 8 waves: waves 0..5 take 2, waves 6,7 take 1
    const int start = (warp < 6) ? warp * 2 : 12 + (warp - 6);
    const int cnt   = (warp < 6) ? 2 : 1;
    unsigned short* ab = attn + (size_t)b * 49 * HW;

#pragma unroll
    for (int u = 0; u < 2; ++u) {
        if (u < cnt) {
            int pxt = start + u;
            f32x4 a2[4];
#pragma unroll
            for (int tt = 0; tt < 4; ++tt)
#pragma unroll
                for (int c = 0; c < 4; ++c) a2[tt][c] = 0.f;
#pragma unroll
            for (int ks = 0; ks < 4; ++ks) {
                const f16x8 ba = *(const f16x8*)(k1sa + (pxt * 16 + li) * 136 + ks * 32 + j * 8);
                const f16x8 bbv = *(const f16x8*)(k1sb + (pxt * 16 + li) * 136 + ks * 32 + j * 8);
                const f16x8 bf = ba + bbv;             // packed fp16 add
#pragma unroll
                for (int tt = 0; tt < 4; ++tt) {
                    const f16x8 af = *(const f16x8*)(w2s + (tt * 16 + li) * 136 + ks * 32 + j * 8);
                    a2[tt] = __builtin_amdgcn_mfma_f32_16x16x32_f16(af, bf, a2[tt], 0, 0, 0);
                }
            }
            // softmax over taps (rows) for pixel col li
            float mx = -3e38f;
#pragma unroll
            for (int tt = 0; tt < 4; ++tt)
#pragma unroll
                for (int i = 0; i < 4; ++i) {
                    int r = tt * 16 + j * 4 + i;
                    float v = a2[tt][i] + ((r < 49) ? b2[r] : 0.f);
                    a2[tt][i] = v;
                    if (r < 49) mx = fmaxf(mx, v);
                }
            mx = fmaxf(mx, __shfl_xor(mx, 16));
            mx = fmaxf(mx, __shfl_xor(mx, 32));
            float sum = 0.f; float ex[16];
#pragma unroll
            for (int tt = 0; tt < 4; ++tt)
#pragma unroll
                for (int i = 0; i < 4; ++i) {
                    int r = tt * 16 + j * 4 + i;
                    float e = (r < 49) ? __expf(a2[tt][i] - mx) : 0.f;
                    ex[tt * 4 + i] = e; sum += e;
                }
            sum += __shfl_xor(sum, 16);
            sum += __shfl_xor(sum, 32);
            float inv = 1.f / sum;

            int s = rg * 224 + pxt * 16 + li;          // pixel within batch
#pragma unroll
            for (int tt = 0; tt < 4; ++tt)
#pragma unroll
                for (int i = 0; i < 4; ++i) {
                    int r = tt * 16 + j * 4 + i;
                    if (r < 49) ab[(size_t)r * HW + s] = f2h(ex[tt * 4 + i] * inv);
                }
        }
    }
}

// ================= final grouped einsum, 8 outputs/thread (r7-proven) =================
__global__ __launch_bounds__(256) void gather_kernel(
    const unsigned short* __restrict__ xpad, const unsigned short* __restrict__ attn,
    float* __restrict__ out)
{
    int tid = blockIdx.x * 256 + threadIdx.x;   // < 401408
    int plane = tid / 392;                      // b*64 + c
    int r1 = tid - plane * 392;
    int h = r1 / 7; int oct = r1 - h * 7; int w0 = oct * 8;
    int F0 = plane * HW + h * 56 + w0;

    const unsigned short* ap = attn + (size_t)(F0 >> 6) * 49;
    float a[49];
#pragma unroll
    for (int k = 0; k < 49; ++k) a[k] = h2f(ap[k]);

    const unsigned short* xp = xpad + (size_t)plane * (68 * 72) + w0;
    float o[8];
#pragma unroll
    for (int dw = 0; dw < 8; ++dw) o[dw] = 0.f;

#pragma unroll
    for (int p = 0; p < 7; ++p) {
        const unsigned short* rp = xp + (h + 2 * p) * 72;
        u16x8 v0 = *(const u16x8*)rp;
        u16x8 v1 = *(const u16x8*)(rp + 8);
        u16x8 v2 = *(const u16x8*)(rp + 16);
        float rr[20];
#pragma unroll
        for (int e = 0; e < 8; ++e) { rr[e] = h2f(v0[e]); rr[8 + e] = h2f(v1[e]); }
#pragma unroll
        for (int e = 0; e < 4; ++e) rr[16 + e] = h2f(v2[e]);
#pragma unroll
        for (int q = 0; q < 7; ++q) {
            float aq = a[p * 7 + q];
#pragma unroll
            for (int dw = 0; dw < 8; ++dw)
                o[dw] = fmaf(rr[dw + 2 * q], aq, o[dw]);
        }
    }

    f32x4 s0 = {o[0], o[1], o[2], o[3]};
    f32x4 s1 = {o[4], o[5], o[6], o[7]};
    *(f32x4*)(out + F0) = s0;
    *(f32x4*)(out + F0 + 4) = s1;
}

extern "C" void kernel_launch(void* const* d_in, const int* in_sizes, int n_in,
                              void* d_out, int out_size, void* d_ws, size_t ws_size,
                              hipStream_t stream)
{
    const float* x  = (const float*)d_in[0];
    const float* w1 = (const float*)d_in[1];
    const float* b1 = (const float*)d_in[2];
    const float* w2 = (const float*)d_in[3];
    const float* b2 = (const float*)d_in[4];
    float* out = (float*)d_out;

    unsigned short* attn = (unsigned short*)d_ws;              //  4.92 MB
    unsigned short* xg   = attn + (size_t)16 * 49 * HW;        //  6.42 MB
    unsigned short* w1t  = xg + (size_t)16 * 2 * HW * 32;      //  0.80 MB
    unsigned short* xpad = w1t + (size_t)2 * 49 * 128 * 32;    // 10.03 MB (total ~22.2 MB)

    prep_all<<<860, 256, 0, stream>>>(x, w1, xg, w1t, xpad);
    conv_full<<<224, 512, 0, stream>>>(xg, w1t, b1, w2, b2, attn);
    gather_kernel<<<1568, 256, 0, stream>>>(xpad, attn, out);
}